// Round 3
// baseline (198.510 us; speedup 1.0000x reference)
//
#include <hip/hip_runtime.h>

#define B_ 2
#define L_ 2048
#define H_ 1024
#define NH_ 16
#define HD_ 64

using short8 = __attribute__((__ext_vector_type__(8))) short;
using f32x4 = __attribute__((__ext_vector_type__(4))) float;
using f32x16 = __attribute__((__ext_vector_type__(16))) float;
typedef unsigned short u16;
typedef unsigned int u32;

__device__ __forceinline__ u16 f2bf(float f) {
  union { float f; unsigned u; } x{f};
  unsigned u = x.u;
  u = u + 0x7FFFu + ((u >> 16) & 1u);  // round-to-nearest-even
  return (u16)(u >> 16);
}

__device__ __forceinline__ void gld16(const void* g, void* l) {
  __builtin_amdgcn_global_load_lds(
      (const __attribute__((address_space(1))) void*)g,
      (__attribute__((address_space(3))) void*)l, 16, 0, 0);
}

#define MFMA16(a, b, c) __builtin_amdgcn_mfma_f32_16x16x32_bf16((a), (b), (c), 0, 0, 0)
#define MFMA32(a, b, c) __builtin_amdgcn_mfma_f32_32x32x16_bf16((a), (b), (c), 0, 0, 0)

// ---------------- cast f32 -> bf16 ----------------
__global__ void castk(const float* __restrict__ src, u16* __restrict__ dst, int n) {
  int i = (blockIdx.x * 256 + threadIdx.x) * 4;
  if (i < n) {
    float4 v = *(const float4*)(src + i);
    ushort4 o = make_ushort4(f2bf(v.x), f2bf(v.y), f2bf(v.z), f2bf(v.w));
    *(ushort4*)(dst + i) = o;
  }
}

// delta -> delta * 0.125 * log2(e)
__global__ void prep_delta(const float* __restrict__ d, float* __restrict__ o, int n) {
  int i = blockIdx.x * 256 + threadIdx.x;
  if (i < n) o[i] = d[i] * 0.18033688011112042f;
}

// ---------------- fused QKV GEMM: [4096,1024] x [3072,1024]^T ----------------
// q (pre-scaled by tau*0.125*log2e), k written [b,h,l,d]; v written transposed [b,h,d,l]
__global__ __launch_bounds__(256) void gemm_qkv(
    const u16* __restrict__ A, const u16* __restrict__ W,
    const float* __restrict__ bq, const float* __restrict__ bk, const float* __restrict__ bv,
    const float* __restrict__ tau,
    u16* __restrict__ qg, u16* __restrict__ kg, u16* __restrict__ vTg) {
  __shared__ u16 As[128 * 64];
  __shared__ u16 Bs[128 * 64];
  const int tid = threadIdx.x;
  const int lane = tid & 63;
  const int wave = tid >> 6;
  const int wrow = (wave >> 1) * 64;
  const int wcol = (wave & 1) * 64;
  const int m0 = blockIdx.y * 128;
  const int n0 = blockIdx.x * 128;
  const int rr = tid >> 3;
  const int c8 = (tid & 7) * 8;
  f32x4 acc[4][4] = {};
  for (int kt = 0; kt < 1024; kt += 64) {
#pragma unroll
    for (int i = 0; i < 4; i++) {
      gld16(A + (size_t)(m0 + i * 32 + rr) * 1024 + kt + c8, (char*)As + i * 4096 + wave * 1024);
      gld16(W + (size_t)(n0 + i * 32 + rr) * 1024 + kt + c8, (char*)Bs + i * 4096 + wave * 1024);
    }
    __syncthreads();
#pragma unroll
    for (int kc = 0; kc < 2; kc++) {
      const int ko = kc * 32 + (lane >> 4) * 8;
      short8 af[4], bf[4];
#pragma unroll
      for (int mi = 0; mi < 4; mi++)
        af[mi] = *(const short8*)&As[(wrow + mi * 16 + (lane & 15)) * 64 + ko];
#pragma unroll
      for (int ni = 0; ni < 4; ni++)
        bf[ni] = *(const short8*)&Bs[(wcol + ni * 16 + (lane & 15)) * 64 + ko];
#pragma unroll
      for (int mi = 0; mi < 4; mi++)
#pragma unroll
        for (int ni = 0; ni < 4; ni++)
          acc[mi][ni] = MFMA16(af[mi], bf[ni], acc[mi][ni]);
    }
    __syncthreads();
  }
  const int which = n0 >> 10;  // 0=q 1=k 2=v, uniform per block
  const int b_blk = m0 >> 11;
  const float scl = (which == 0) ? tau[b_blk] * 0.18033688011112042f : 1.0f;
  const float* bias = which == 0 ? bq : (which == 1 ? bk : bv);
#pragma unroll
  for (int ni = 0; ni < 4; ni++) {
    const int n = n0 + wcol + ni * 16 + (lane & 15);
    const int nn = n & 1023;
    const int h = nn >> 6, d = nn & 63;
    const float bb = bias[nn];
#pragma unroll
    for (int mi = 0; mi < 4; mi++) {
      const int mb = m0 + wrow + mi * 16 + ((lane >> 4) << 2);
      const int b = mb >> 11;
      const int lq = mb & 2047;
      if (which == 2) {
        ushort4 pk = make_ushort4(f2bf(acc[mi][ni][0] + bb), f2bf(acc[mi][ni][1] + bb),
                                  f2bf(acc[mi][ni][2] + bb), f2bf(acc[mi][ni][3] + bb));
        *(ushort4*)&vTg[((size_t)(b * NH_ + h) * HD_ + d) * L_ + lq] = pk;
      } else {
        u16* dst = which == 0 ? qg : kg;
#pragma unroll
        for (int r = 0; r < 4; r++)
          dst[((size_t)(b * NH_ + h) * L_ + lq + r) * HD_ + d] = f2bf((acc[mi][ni][r] + bb) * scl);
      }
    }
  }
}

// ---------------- flash attention, swapped-QK^T 32x32x16, intra-block key-split ----------------
// grid (L/64, B*NH), 256 threads. Wave w: q-rows [bx*64 + (w&1)*32, +32), keys [(w>>1)*1024, +1024).
// Wave pairs (0,2),(1,3) merge partial flash states at the end.
__global__ __launch_bounds__(256) void attn(
    const u16* __restrict__ qg, const u16* __restrict__ kg, const u16* __restrict__ vTg,
    const float* __restrict__ dsc, u16* __restrict__ ctxg) {
  // per buffer (16KB): 8 K blocks (2 streams x 4 ks) + 8 V blocks (2 streams x 2 dt x 2 ks2), 1KB each
  __shared__ u16 lds[2][8192];
  const int tid = threadIdx.x;
  const int lane = tid & 63;
  const int wv = tid >> 6;
  const int lane31 = lane & 31;
  const int hi = lane >> 5;
  const int qsub = wv & 1;
  const int kh = wv >> 1;
  const int bh = blockIdx.y;
  const int b = bh >> 4;
  const int h = bh & 15;
  const int q0 = blockIdx.x * 64 + qsub * 32;
  const u16* qb = qg + (size_t)bh * L_ * HD_;
  const u16* kb = kg + (size_t)bh * L_ * HD_;
  const u16* vb = vTg + (size_t)bh * HD_ * L_;
  const float* db = dsc + (size_t)b * L_;

  // Q fragments (B-operand): lane holds Q[q0+lane31][ks*16 + hi*8 .. +7]
  short8 qf[4];
#pragma unroll
  for (int ks = 0; ks < 4; ks++)
    qf[ks] = *(const short8*)&qb[(size_t)(q0 + lane31) * 64 + ks * 16 + hi * 8];

  f32x16 acc[2] = {};  // ctx^T: [dtile] rows d=crow(r,hi), col q=lane31
  float mrun = -__builtin_inff(), lrun = 0.f;

  // staging: waves 0,1 load K streams 0,1; waves 2,3 load V streams 0,1 (4 x gld16 each)
#define STAGE(bufi, j)                                                                 \
  {                                                                                    \
    u16* bp = lds[bufi];                                                               \
    if (wv < 2) {                                                                      \
      const u16* src = kb + (size_t)(wv * 1024 + (j) + lane31) * 64 + hi * 8;          \
      gld16(src, bp + (wv * 4 + 0) * 512 + lane * 8);                                  \
      gld16(src + 16, bp + (wv * 4 + 1) * 512 + lane * 8);                             \
      gld16(src + 32, bp + (wv * 4 + 2) * 512 + lane * 8);                             \
      gld16(src + 48, bp + (wv * 4 + 3) * 512 + lane * 8);                             \
    } else {                                                                           \
      const int st = wv & 1;                                                           \
      const u16* vsrc = vb + (size_t)lane31 * L_ + st * 1024 + (j) + hi * 8;           \
      gld16(vsrc, bp + (8 + st * 4 + 0) * 512 + lane * 8);                             \
      gld16(vsrc + 16, bp + (8 + st * 4 + 1) * 512 + lane * 8);                        \
      gld16(vsrc + (size_t)32 * L_, bp + (8 + st * 4 + 2) * 512 + lane * 8);           \
      gld16(vsrc + (size_t)32 * L_ + 16, bp + (8 + st * 4 + 3) * 512 + lane * 8);      \
    }                                                                                  \
  }

  STAGE(0, 0);
  __syncthreads();
  int cur = 0;
  for (int j = 0; j < 1024; j += 32) {
    if (j + 32 < 1024) STAGE(cur ^ 1, j + 32);
    const u16* bp = lds[cur];
    // S^T = K . Q^T : lane holds col q=lane31, rows key=crow(r,hi)
    f32x16 s = {};
#pragma unroll
    for (int ks = 0; ks < 4; ks++) {
      short8 kf = *(const short8*)&bp[(kh * 4 + ks) * 512 + lane * 8];
      s = MFMA32(kf, qf[ks], s);
    }
    const int jj = kh * 1024 + j;
    float sv[16];
#pragma unroll
    for (int g = 0; g < 4; g++) {
      float4 dl = *(const float4*)&db[jj + g * 8 + hi * 4];
      sv[g * 4 + 0] = s[g * 4 + 0] + dl.x;
      sv[g * 4 + 1] = s[g * 4 + 1] + dl.y;
      sv[g * 4 + 2] = s[g * 4 + 2] + dl.z;
      sv[g * 4 + 3] = s[g * 4 + 3] + dl.w;
    }
    // row max (15 local + 1 cross-half shuffle)
    float t0 = fmaxf(fmaxf(sv[0], sv[1]), fmaxf(sv[2], sv[3]));
    float t1 = fmaxf(fmaxf(sv[4], sv[5]), fmaxf(sv[6], sv[7]));
    float t2 = fmaxf(fmaxf(sv[8], sv[9]), fmaxf(sv[10], sv[11]));
    float t3 = fmaxf(fmaxf(sv[12], sv[13]), fmaxf(sv[14], sv[15]));
    float pmax = fmaxf(fmaxf(t0, t1), fmaxf(t2, t3));
    pmax = fmaxf(pmax, __shfl_xor(pmax, 32));
    // defer-max (THR = 8 * log2e ~ 11.54)
    if (!__all(pmax - mrun <= 11.5f)) {
      float mnew = fmaxf(mrun, pmax);
      float al = __builtin_amdgcn_exp2f(mrun - mnew);
      mrun = mnew;
      lrun *= al;
#pragma unroll
      for (int dt = 0; dt < 2; dt++)
#pragma unroll
        for (int r = 0; r < 16; r++) acc[dt][r] *= al;
    }
    float p[16];
#pragma unroll
    for (int r = 0; r < 16; r++) p[r] = __builtin_amdgcn_exp2f(sv[r] - mrun);
    float r0 = (p[0] + p[1]) + (p[2] + p[3]);
    float r1 = (p[4] + p[5]) + (p[6] + p[7]);
    float r2 = (p[8] + p[9]) + (p[10] + p[11]);
    float r3 = (p[12] + p[13]) + (p[14] + p[15]);
    float rs = (r0 + r1) + (r2 + r3);
    rs += __shfl_xor(rs, 32);
    lrun += rs;
    // T12: pack to bf16 pairs, permlane32_swap to build PV B-fragments in-register
    u32 pk[8];
#pragma unroll
    for (int i = 0; i < 8; i++)
      asm("v_cvt_pk_bf16_f32 %0, %1, %2" : "=v"(pk[i]) : "v"(p[2 * i]), "v"(p[2 * i + 1]));
    asm volatile("v_permlane32_swap_b32 %0, %1" : "+v"(pk[0]), "+v"(pk[2]));
    asm volatile("v_permlane32_swap_b32 %0, %1" : "+v"(pk[1]), "+v"(pk[3]));
    asm volatile("v_permlane32_swap_b32 %0, %1" : "+v"(pk[4]), "+v"(pk[6]));
    asm volatile("v_permlane32_swap_b32 %0, %1" : "+v"(pk[5]), "+v"(pk[7]));
    union U8 { u32 u[4]; short8 s; } f0, f1;
    f0.u[0] = pk[0]; f0.u[1] = pk[1]; f0.u[2] = pk[2]; f0.u[3] = pk[3];
    f1.u[0] = pk[4]; f1.u[1] = pk[5]; f1.u[2] = pk[6]; f1.u[3] = pk[7];
    // ctx^T += V^T . P
#pragma unroll
    for (int ks2 = 0; ks2 < 2; ks2++) {
      short8 pf = ks2 ? f1.s : f0.s;
#pragma unroll
      for (int dt = 0; dt < 2; dt++) {
        short8 vf = *(const short8*)&bp[(8 + kh * 4 + dt * 2 + ks2) * 512 + lane * 8];
        acc[dt] = MFMA32(vf, pf, acc[dt]);
      }
    }
    __syncthreads();
    cur ^= 1;
  }

  // ---- merge wave pairs (w, w+2): waves 2,3 publish state, waves 0,1 combine ----
  float* cacc = (float*)lds[1];                     // [p][32][64] f32, 16KB
  float* cml = (float*)(lds[0] + 4096);             // [p][2][64] f32, 1KB (bytes 8192..9215)
  if (wv >= 2) {
    const int p = wv & 1;
#pragma unroll
    for (int dt = 0; dt < 2; dt++)
#pragma unroll
      for (int r = 0; r < 16; r++)
        cacc[(size_t)p * 2048 + (dt * 16 + r) * 64 + lane] = acc[dt][r];
    cml[p * 128 + lane] = mrun;
    cml[p * 128 + 64 + lane] = lrun;
  }
  __syncthreads();
  if (wv < 2) {
    const float m1 = cml[wv * 128 + lane];
    const float l1 = cml[wv * 128 + 64 + lane];
    const float mn = fmaxf(mrun, m1);
    const float a0 = __builtin_amdgcn_exp2f(mrun - mn);
    const float a1 = __builtin_amdgcn_exp2f(m1 - mn);
    const float inv = 1.0f / (lrun * a0 + l1 * a1);
#pragma unroll
    for (int dt = 0; dt < 2; dt++)
#pragma unroll
      for (int r = 0; r < 16; r++)
        acc[dt][r] = acc[dt][r] * a0 + cacc[(size_t)wv * 2048 + (dt * 16 + r) * 64 + lane] * a1;
    // epilogue: transpose ctx^T -> ctx via swizzled per-wave LDS tile, coalesced store
    u16* tw = lds[0] + wv * 2048;  // 4KB per wave: [32 q][64 d] bf16, XOR-swizzled
#pragma unroll
    for (int dt = 0; dt < 2; dt++)
#pragma unroll
      for (int g = 0; g < 4; g++) {
        ushort4 w4 = make_ushort4(f2bf(acc[dt][g * 4 + 0] * inv), f2bf(acc[dt][g * 4 + 1] * inv),
                                  f2bf(acc[dt][g * 4 + 2] * inv), f2bf(acc[dt][g * 4 + 3] * inv));
        const int d0 = dt * 32 + g * 8 + hi * 4;
        const int byte = (lane31 * 128 + d0 * 2) ^ ((lane31 & 15) << 3);
        *(ushort4*)((char*)tw + byte) = w4;
      }
    asm volatile("s_waitcnt lgkmcnt(0)" ::: "memory");
    const size_t obase = ((size_t)b * L_ + q0) * 1024 + h * 64;
#pragma unroll
    for (int i = 0; i < 16; i++) {
      const int qr = 2 * i + hi;
      const int byte = (qr * 128 + lane31 * 4) ^ ((qr & 15) << 3);
      const u32 val = *(const u32*)((const char*)tw + byte);
      *(u32*)&ctxg[obase + (size_t)qr * 1024 + lane31 * 2] = val;
    }
  }
}

// ---------------- output GEMM: ctx[4096,1024] x Wo[1024,1024]^T + bo -> f32 ----------------
__global__ __launch_bounds__(256) void gemm_out(
    const u16* __restrict__ A, const u16* __restrict__ W,
    const float* __restrict__ bo, float* __restrict__ out) {
  __shared__ u16 As[128 * 64];
  __shared__ u16 Bs[128 * 64];
  const int tid = threadIdx.x;
  const int lane = tid & 63;
  const int wave = tid >> 6;
  const int wrow = (wave >> 1) * 64;
  const int wcol = (wave & 1) * 64;
  const int m0 = blockIdx.y * 128;
  const int n0 = blockIdx.x * 128;
  const int rr = tid >> 3;
  const int c8 = (tid & 7) * 8;
  f32x4 acc[4][4] = {};
  for (int kt = 0; kt < 1024; kt += 64) {
#pragma unroll
    for (int i = 0; i < 4; i++) {
      gld16(A + (size_t)(m0 + i * 32 + rr) * 1024 + kt + c8, (char*)As + i * 4096 + wave * 1024);
      gld16(W + (size_t)(n0 + i * 32 + rr) * 1024 + kt + c8, (char*)Bs + i * 4096 + wave * 1024);
    }
    __syncthreads();
#pragma unroll
    for (int kc = 0; kc < 2; kc++) {
      const int ko = kc * 32 + (lane >> 4) * 8;
      short8 af[4], bf[4];
#pragma unroll
      for (int mi = 0; mi < 4; mi++)
        af[mi] = *(const short8*)&As[(wrow + mi * 16 + (lane & 15)) * 64 + ko];
#pragma unroll
      for (int ni = 0; ni < 4; ni++)
        bf[ni] = *(const short8*)&Bs[(wcol + ni * 16 + (lane & 15)) * 64 + ko];
#pragma unroll
      for (int mi = 0; mi < 4; mi++)
#pragma unroll
        for (int ni = 0; ni < 4; ni++)
          acc[mi][ni] = MFMA16(af[mi], bf[ni], acc[mi][ni]);
    }
    __syncthreads();
  }
#pragma unroll
  for (int ni = 0; ni < 4; ni++) {
    const int n = n0 + wcol + ni * 16 + (lane & 15);
    const float bb = bo[n];
#pragma unroll
    for (int mi = 0; mi < 4; mi++) {
      const int mb = m0 + wrow + mi * 16 + ((lane >> 4) << 2);
#pragma unroll
      for (int r = 0; r < 4; r++)
        out[(size_t)(mb + r) * 1024 + n] = acc[mi][ni][r] + bb;
    }
  }
}

extern "C" void kernel_launch(void* const* d_in, const int* in_sizes, int n_in,
                              void* d_out, int out_size, void* d_ws, size_t ws_size,
                              hipStream_t stream) {
  const float* hs = (const float*)d_in[0];
  const float* tau = (const float*)d_in[1];
  const float* delta = (const float*)d_in[2];
  const float* Wq = (const float*)d_in[3];
  const float* bq = (const float*)d_in[4];
  const float* Wk = (const float*)d_in[5];
  const float* bk = (const float*)d_in[6];
  const float* Wv = (const float*)d_in[7];
  const float* bv = (const float*)d_in[8];
  const float* Wo = (const float*)d_in[9];
  const float* bo = (const float*)d_in[10];
  float* out = (float*)d_out;

  u16* ws = (u16*)d_ws;
  u16* hsb  = ws;                   // 4194304
  u16* wqkv = ws + 4194304;         // 3145728 (Wq|Wk|Wv)
  u16* wob  = ws + 7340032;         // 1048576
  u16* qg   = ws + 8388608;         // 4194304
  u16* kg   = ws + 12582912;        // 4194304
  u16* vTg  = ws + 16777216;        // 4194304
  u16* ctxg = ws + 20971520;        // 4194304
  float* dsc = (float*)(ws + 25165824);  // 4096 floats

  castk<<<4096, 256, 0, stream>>>(hs, hsb, 4194304);
  castk<<<1024, 256, 0, stream>>>(Wq, wqkv, 1048576);
  castk<<<1024, 256, 0, stream>>>(Wk, wqkv + 1048576, 1048576);
  castk<<<1024, 256, 0, stream>>>(Wv, wqkv + 2097152, 1048576);
  castk<<<1024, 256, 0, stream>>>(Wo, wob, 1048576);
  prep_delta<<<16, 256, 0, stream>>>(delta, dsc, 4096);

  gemm_qkv<<<dim3(24, 32), 256, 0, stream>>>(hsb, wqkv, bq, bk, bv, tau, qg, kg, vTg);
  attn<<<dim3(32, 32), 256, 0, stream>>>(qg, kg, vTg, dsc, ctxg);
  gemm_out<<<dim3(8, 32), 256, 0, stream>>>(ctxg, wob, bo, out);
}

// Round 4
// 186.849 us; speedup vs baseline: 1.0624x; 1.0624x over previous
//
#include <hip/hip_runtime.h>

#define B_ 2
#define L_ 2048
#define H_ 1024
#define NH_ 16
#define HD_ 64

using short8 = __attribute__((__ext_vector_type__(8))) short;
using f32x4 = __attribute__((__ext_vector_type__(4))) float;
using f32x16 = __attribute__((__ext_vector_type__(16))) float;
typedef unsigned short u16;
typedef unsigned int u32;

__device__ __forceinline__ u16 f2bf(float f) {
  union { float f; unsigned u; } x{f};
  unsigned u = x.u;
  u = u + 0x7FFFu + ((u >> 16) & 1u);  // round-to-nearest-even
  return (u16)(u >> 16);
}

__device__ __forceinline__ void gld16(const void* g, void* l) {
  __builtin_amdgcn_global_load_lds(
      (const __attribute__((address_space(1))) void*)g,
      (__attribute__((address_space(3))) void*)l, 16, 0, 0);
}

#define MFMA16(a, b, c) __builtin_amdgcn_mfma_f32_16x16x32_bf16((a), (b), (c), 0, 0, 0)
#define MFMA32(a, b, c) __builtin_amdgcn_mfma_f32_32x32x16_bf16((a), (b), (c), 0, 0, 0)

// ---------------- cast f32 -> bf16 ----------------
__global__ void castk(const float* __restrict__ src, u16* __restrict__ dst, int n) {
  int i = (blockIdx.x * 256 + threadIdx.x) * 4;
  if (i < n) {
    float4 v = *(const float4*)(src + i);
    ushort4 o = make_ushort4(f2bf(v.x), f2bf(v.y), f2bf(v.z), f2bf(v.w));
    *(ushort4*)(dst + i) = o;
  }
}

// delta -> delta * 0.125 * log2(e)
__global__ void prep_delta(const float* __restrict__ d, float* __restrict__ o, int n) {
  int i = blockIdx.x * 256 + threadIdx.x;
  if (i < n) o[i] = d[i] * 0.18033688011112042f;
}

// ---------------- fused QKV GEMM: [4096,1024] x [3072,1024]^T ----------------
// q (pre-scaled by tau*0.125*log2e), k written [b,h,l,d]; v written transposed [b,h,d,l]
__global__ __launch_bounds__(256) void gemm_qkv(
    const u16* __restrict__ A, const u16* __restrict__ W,
    const float* __restrict__ bq, const float* __restrict__ bk, const float* __restrict__ bv,
    const float* __restrict__ tau,
    u16* __restrict__ qg, u16* __restrict__ kg, u16* __restrict__ vTg) {
  __shared__ u16 As[128 * 64];
  __shared__ u16 Bs[128 * 64];
  const int tid = threadIdx.x;
  const int lane = tid & 63;
  const int wave = tid >> 6;
  const int wrow = (wave >> 1) * 64;
  const int wcol = (wave & 1) * 64;
  const int m0 = blockIdx.y * 128;
  const int n0 = blockIdx.x * 128;
  const int rr = tid >> 3;
  const int c8 = (tid & 7) * 8;
  f32x4 acc[4][4] = {};
  for (int kt = 0; kt < 1024; kt += 64) {
#pragma unroll
    for (int i = 0; i < 4; i++) {
      gld16(A + (size_t)(m0 + i * 32 + rr) * 1024 + kt + c8, (char*)As + i * 4096 + wave * 1024);
      gld16(W + (size_t)(n0 + i * 32 + rr) * 1024 + kt + c8, (char*)Bs + i * 4096 + wave * 1024);
    }
    __syncthreads();
#pragma unroll
    for (int kc = 0; kc < 2; kc++) {
      const int ko = kc * 32 + (lane >> 4) * 8;
      short8 af[4], bf[4];
#pragma unroll
      for (int mi = 0; mi < 4; mi++)
        af[mi] = *(const short8*)&As[(wrow + mi * 16 + (lane & 15)) * 64 + ko];
#pragma unroll
      for (int ni = 0; ni < 4; ni++)
        bf[ni] = *(const short8*)&Bs[(wcol + ni * 16 + (lane & 15)) * 64 + ko];
#pragma unroll
      for (int mi = 0; mi < 4; mi++)
#pragma unroll
        for (int ni = 0; ni < 4; ni++)
          acc[mi][ni] = MFMA16(af[mi], bf[ni], acc[mi][ni]);
    }
    __syncthreads();
  }
  const int which = n0 >> 10;  // 0=q 1=k 2=v, uniform per block
  const int b_blk = m0 >> 11;
  const float scl = (which == 0) ? tau[b_blk] * 0.18033688011112042f : 1.0f;
  const float* bias = which == 0 ? bq : (which == 1 ? bk : bv);
#pragma unroll
  for (int ni = 0; ni < 4; ni++) {
    const int n = n0 + wcol + ni * 16 + (lane & 15);
    const int nn = n & 1023;
    const int h = nn >> 6, d = nn & 63;
    const float bb = bias[nn];
#pragma unroll
    for (int mi = 0; mi < 4; mi++) {
      const int mb = m0 + wrow + mi * 16 + ((lane >> 4) << 2);
      const int b = mb >> 11;
      const int lq = mb & 2047;
      if (which == 2) {
        ushort4 pk = make_ushort4(f2bf(acc[mi][ni][0] + bb), f2bf(acc[mi][ni][1] + bb),
                                  f2bf(acc[mi][ni][2] + bb), f2bf(acc[mi][ni][3] + bb));
        *(ushort4*)&vTg[((size_t)(b * NH_ + h) * HD_ + d) * L_ + lq] = pk;
      } else {
        u16* dst = which == 0 ? qg : kg;
#pragma unroll
        for (int r = 0; r < 4; r++)
          dst[((size_t)(b * NH_ + h) * L_ + lq + r) * HD_ + d] = f2bf((acc[mi][ni][r] + bb) * scl);
      }
    }
  }
}

// ---------------- flash attention, swapped-QK^T 32x32x16, 2-wave blocks ----------------
// grid (32,32) remapped XCD-chunked; 128 threads; each wave owns 32 q-rows x all 2048 keys.
__global__ __launch_bounds__(128) void attn(
    const u16* __restrict__ qg, const u16* __restrict__ kg, const u16* __restrict__ vTg,
    const float* __restrict__ dsc, u16* __restrict__ ctxg) {
  // per buffer (16KB): 8 K blocks (2 kt x 4 ks) + 8 V blocks (2 kt x 2 dt x 2 ks2), 1KB each
  __shared__ u16 lds[2][8192];
  const int tid = threadIdx.x;
  const int lane = tid & 63;
  const int wv = tid >> 6;
  const int lane31 = lane & 31;
  const int hi = lane >> 5;
  // bijective XCD-chunk swizzle: nwg=1024, 8 XCDs -> 128 consecutive wgids per XCD
  const int orig = blockIdx.y * 32 + blockIdx.x;
  const int wgid = (orig & 7) * 128 + (orig >> 3);
  const int bh = wgid >> 5;       // 4 consecutive bh per XCD -> 4MB K/V in L2
  const int qblk = wgid & 31;
  const int b = bh >> 4;
  const int h = bh & 15;
  const int q0 = qblk * 64 + wv * 32;
  const u16* qb = qg + (size_t)bh * L_ * HD_;
  const u16* kb = kg + (size_t)bh * L_ * HD_;
  const u16* vb = vTg + (size_t)bh * HD_ * L_;
  const float* db = dsc + (size_t)b * L_;

  // Q fragments (B-operand): lane holds Q[q0+lane31][ks*16 + hi*8 .. +7]
  short8 qf[4];
#pragma unroll
  for (int ks = 0; ks < 4; ks++)
    qf[ks] = *(const short8*)&qb[(size_t)(q0 + lane31) * 64 + ks * 16 + hi * 8];

  f32x16 acc[2] = {};  // ctx^T: [dtile] rows d=crow(r,hi), col q=lane31
  float mrun = -__builtin_inff(), lrun = 0.f;

  // staging: wave wv stages kt=wv slice (4 K gld16 + 4 V gld16)
#define STAGE(bufi, j0_)                                                            \
  {                                                                                 \
    u16* bp = lds[bufi];                                                            \
    const u16* ksrc = kb + (size_t)((j0_) + wv * 32 + lane31) * 64 + hi * 8;        \
    gld16(ksrc,      bp + (wv * 4 + 0) * 512 + lane * 8);                           \
    gld16(ksrc + 16, bp + (wv * 4 + 1) * 512 + lane * 8);                           \
    gld16(ksrc + 32, bp + (wv * 4 + 2) * 512 + lane * 8);                           \
    gld16(ksrc + 48, bp + (wv * 4 + 3) * 512 + lane * 8);                           \
    const u16* vsrc = vb + (size_t)lane31 * L_ + (j0_) + wv * 32 + hi * 8;          \
    gld16(vsrc,                        bp + (8 + wv * 4 + 0) * 512 + lane * 8);     \
    gld16(vsrc + 16,                   bp + (8 + wv * 4 + 1) * 512 + lane * 8);     \
    gld16(vsrc + (size_t)32 * L_,      bp + (8 + wv * 4 + 2) * 512 + lane * 8);     \
    gld16(vsrc + (size_t)32 * L_ + 16, bp + (8 + wv * 4 + 3) * 512 + lane * 8);     \
  }

  STAGE(0, 0);
  __syncthreads();
  int cur = 0;
  for (int j0 = 0; j0 < L_; j0 += 64) {
    if (j0 + 64 < L_) STAGE(cur ^ 1, j0 + 64);
    const u16* bp = lds[cur];
    // S^T for both 32-key tiles: two independent MFMA chains
    f32x16 s0v = {}, s1v = {};
#pragma unroll
    for (int ks = 0; ks < 4; ks++) {
      short8 kf0 = *(const short8*)&bp[(0 * 4 + ks) * 512 + lane * 8];
      short8 kf1 = *(const short8*)&bp[(1 * 4 + ks) * 512 + lane * 8];
      s0v = MFMA32(kf0, qf[ks], s0v);
      s1v = MFMA32(kf1, qf[ks], s1v);
    }
    // sv = s + delta (pre-scaled, log2 units); 32 scores per lane
    float sv[32];
#pragma unroll
    for (int g = 0; g < 4; g++) {
      float4 dl0 = *(const float4*)&db[j0 + g * 8 + hi * 4];
      float4 dl1 = *(const float4*)&db[j0 + 32 + g * 8 + hi * 4];
      sv[g * 4 + 0] = s0v[g * 4 + 0] + dl0.x;
      sv[g * 4 + 1] = s0v[g * 4 + 1] + dl0.y;
      sv[g * 4 + 2] = s0v[g * 4 + 2] + dl0.z;
      sv[g * 4 + 3] = s0v[g * 4 + 3] + dl0.w;
      sv[16 + g * 4 + 0] = s1v[g * 4 + 0] + dl1.x;
      sv[16 + g * 4 + 1] = s1v[g * 4 + 1] + dl1.y;
      sv[16 + g * 4 + 2] = s1v[g * 4 + 2] + dl1.z;
      sv[16 + g * 4 + 3] = s1v[g * 4 + 3] + dl1.w;
    }
    // single max-tree over 64 keys
    float tm[16];
#pragma unroll
    for (int r = 0; r < 16; r++) tm[r] = fmaxf(sv[r], sv[16 + r]);
#pragma unroll
    for (int r = 0; r < 8; r++) tm[r] = fmaxf(tm[r], tm[8 + r]);
#pragma unroll
    for (int r = 0; r < 4; r++) tm[r] = fmaxf(tm[r], tm[4 + r]);
    float pmax = fmaxf(fmaxf(tm[0], tm[1]), fmaxf(tm[2], tm[3]));
    pmax = fmaxf(pmax, __shfl_xor(pmax, 32));
    // defer-max (THR = 8 * log2e ~ 11.54)
    if (!__all(pmax - mrun <= 11.5f)) {
      float mnew = fmaxf(mrun, pmax);
      float al = __builtin_amdgcn_exp2f(mrun - mnew);
      mrun = mnew;
      lrun *= al;
#pragma unroll
      for (int dt = 0; dt < 2; dt++)
#pragma unroll
        for (int r = 0; r < 16; r++) acc[dt][r] *= al;
    }
#pragma unroll
    for (int r = 0; r < 32; r++) sv[r] = __builtin_amdgcn_exp2f(sv[r] - mrun);
    // single sum-tree
    float ts[16];
#pragma unroll
    for (int r = 0; r < 16; r++) ts[r] = sv[r] + sv[16 + r];
#pragma unroll
    for (int r = 0; r < 8; r++) ts[r] = ts[r] + ts[8 + r];
#pragma unroll
    for (int r = 0; r < 4; r++) ts[r] = ts[r] + ts[4 + r];
    float rs = (ts[0] + ts[1]) + (ts[2] + ts[3]);
    rs += __shfl_xor(rs, 32);
    lrun += rs;
    // T12: pack to bf16 pairs, permlane32_swap to build PV B-fragments in-register
    u32 pk[16];
#pragma unroll
    for (int i = 0; i < 16; i++)
      asm("v_cvt_pk_bf16_f32 %0, %1, %2" : "=v"(pk[i]) : "v"(sv[2 * i]), "v"(sv[2 * i + 1]));
#pragma unroll
    for (int kt = 0; kt < 2; kt++) {
      asm volatile("v_permlane32_swap_b32 %0, %1" : "+v"(pk[kt * 8 + 0]), "+v"(pk[kt * 8 + 2]));
      asm volatile("v_permlane32_swap_b32 %0, %1" : "+v"(pk[kt * 8 + 1]), "+v"(pk[kt * 8 + 3]));
      asm volatile("v_permlane32_swap_b32 %0, %1" : "+v"(pk[kt * 8 + 4]), "+v"(pk[kt * 8 + 6]));
      asm volatile("v_permlane32_swap_b32 %0, %1" : "+v"(pk[kt * 8 + 5]), "+v"(pk[kt * 8 + 7]));
    }
    // ctx^T += V^T . P  (both kt tiles)
#pragma unroll
    for (int kt = 0; kt < 2; kt++)
#pragma unroll
      for (int ks2 = 0; ks2 < 2; ks2++) {
        union U8 { u32 u[4]; short8 s; } pf;
        pf.u[0] = pk[kt * 8 + ks2 * 4 + 0];
        pf.u[1] = pk[kt * 8 + ks2 * 4 + 1];
        pf.u[2] = pk[kt * 8 + ks2 * 4 + 2];
        pf.u[3] = pk[kt * 8 + ks2 * 4 + 3];
#pragma unroll
        for (int dt = 0; dt < 2; dt++) {
          short8 vf = *(const short8*)&bp[(8 + kt * 4 + dt * 2 + ks2) * 512 + lane * 8];
          acc[dt] = MFMA32(vf, pf.s, acc[dt]);
        }
      }
    __syncthreads();
    cur ^= 1;
  }

  // epilogue: transpose ctx^T -> ctx via swizzled per-wave LDS tile, coalesced store
  u16* tw = lds[0] + wv * 2048;  // 4KB per wave: [32 q][64 d] bf16, XOR-swizzled
  const float inv = 1.0f / lrun;
#pragma unroll
  for (int dt = 0; dt < 2; dt++)
#pragma unroll
    for (int g = 0; g < 4; g++) {
      ushort4 w4 = make_ushort4(f2bf(acc[dt][g * 4 + 0] * inv), f2bf(acc[dt][g * 4 + 1] * inv),
                                f2bf(acc[dt][g * 4 + 2] * inv), f2bf(acc[dt][g * 4 + 3] * inv));
      const int d0 = dt * 32 + g * 8 + hi * 4;
      const int byte = (lane31 * 128 + d0 * 2) ^ ((lane31 & 15) << 3);
      *(ushort4*)((char*)tw + byte) = w4;
    }
  asm volatile("s_waitcnt lgkmcnt(0)" ::: "memory");
  const size_t obase = ((size_t)b * L_ + q0) * 1024 + h * 64;
#pragma unroll
  for (int i = 0; i < 16; i++) {
    const int qr = 2 * i + hi;
    const int byte = (qr * 128 + lane31 * 4) ^ ((qr & 15) << 3);
    const u32 val = *(const u32*)((const char*)tw + byte);
    *(u32*)&ctxg[obase + (size_t)qr * 1024 + lane31 * 2] = val;
  }
}

// ---------------- output GEMM: ctx[4096,1024] x Wo[1024,1024]^T + bo -> f32 ----------------
__global__ __launch_bounds__(256) void gemm_out(
    const u16* __restrict__ A, const u16* __restrict__ W,
    const float* __restrict__ bo, float* __restrict__ out) {
  __shared__ u16 As[128 * 64];
  __shared__ u16 Bs[128 * 64];
  const int tid = threadIdx.x;
  const int lane = tid & 63;
  const int wave = tid >> 6;
  const int wrow = (wave >> 1) * 64;
  const int wcol = (wave & 1) * 64;
  const int m0 = blockIdx.y * 128;
  const int n0 = blockIdx.x * 128;
  const int rr = tid >> 3;
  const int c8 = (tid & 7) * 8;
  f32x4 acc[4][4] = {};
  for (int kt = 0; kt < 1024; kt += 64) {
#pragma unroll
    for (int i = 0; i < 4; i++) {
      gld16(A + (size_t)(m0 + i * 32 + rr) * 1024 + kt + c8, (char*)As + i * 4096 + wave * 1024);
      gld16(W + (size_t)(n0 + i * 32 + rr) * 1024 + kt + c8, (char*)Bs + i * 4096 + wave * 1024);
    }
    __syncthreads();
#pragma unroll
    for (int kc = 0; kc < 2; kc++) {
      const int ko = kc * 32 + (lane >> 4) * 8;
      short8 af[4], bf[4];
#pragma unroll
      for (int mi = 0; mi < 4; mi++)
        af[mi] = *(const short8*)&As[(wrow + mi * 16 + (lane & 15)) * 64 + ko];
#pragma unroll
      for (int ni = 0; ni < 4; ni++)
        bf[ni] = *(const short8*)&Bs[(wcol + ni * 16 + (lane & 15)) * 64 + ko];
#pragma unroll
      for (int mi = 0; mi < 4; mi++)
#pragma unroll
        for (int ni = 0; ni < 4; ni++)
          acc[mi][ni] = MFMA16(af[mi], bf[ni], acc[mi][ni]);
    }
    __syncthreads();
  }
#pragma unroll
  for (int ni = 0; ni < 4; ni++) {
    const int n = n0 + wcol + ni * 16 + (lane & 15);
    const float bb = bo[n];
#pragma unroll
    for (int mi = 0; mi < 4; mi++) {
      const int mb = m0 + wrow + mi * 16 + ((lane >> 4) << 2);
#pragma unroll
      for (int r = 0; r < 4; r++)
        out[(size_t)(mb + r) * 1024 + n] = acc[mi][ni][r] + bb;
    }
  }
}

extern "C" void kernel_launch(void* const* d_in, const int* in_sizes, int n_in,
                              void* d_out, int out_size, void* d_ws, size_t ws_size,
                              hipStream_t stream) {
  const float* hs = (const float*)d_in[0];
  const float* tau = (const float*)d_in[1];
  const float* delta = (const float*)d_in[2];
  const float* Wq = (const float*)d_in[3];
  const float* bq = (const float*)d_in[4];
  const float* Wk = (const float*)d_in[5];
  const float* bk = (const float*)d_in[6];
  const float* Wv = (const float*)d_in[7];
  const float* bv = (const float*)d_in[8];
  const float* Wo = (const float*)d_in[9];
  const float* bo = (const float*)d_in[10];
  float* out = (float*)d_out;

  u16* ws = (u16*)d_ws;
  u16* hsb  = ws;                   // 4194304
  u16* wqkv = ws + 4194304;         // 3145728 (Wq|Wk|Wv)
  u16* wob  = ws + 7340032;         // 1048576
  u16* qg   = ws + 8388608;         // 4194304
  u16* kg   = ws + 12582912;        // 4194304
  u16* vTg  = ws + 16777216;        // 4194304
  u16* ctxg = ws + 20971520;        // 4194304
  float* dsc = (float*)(ws + 25165824);  // 4096 floats

  castk<<<4096, 256, 0, stream>>>(hs, hsb, 4194304);
  castk<<<1024, 256, 0, stream>>>(Wq, wqkv, 1048576);
  castk<<<1024, 256, 0, stream>>>(Wk, wqkv + 1048576, 1048576);
  castk<<<1024, 256, 0, stream>>>(Wv, wqkv + 2097152, 1048576);
  castk<<<1024, 256, 0, stream>>>(Wo, wob, 1048576);
  prep_delta<<<16, 256, 0, stream>>>(delta, dsc, 4096);

  gemm_qkv<<<dim3(24, 32), 256, 0, stream>>>(hsb, wqkv, bq, bk, bv, tau, qg, kg, vTg);
  attn<<<dim3(32, 32), 128, 0, stream>>>(qg, kg, vTg, dsc, ctxg);
  gemm_out<<<dim3(8, 32), 256, 0, stream>>>(ctxg, wob, bo, out);
}

// Round 5
// 165.160 us; speedup vs baseline: 1.2019x; 1.1313x over previous
//
#include <hip/hip_runtime.h>

#define B_ 2
#define L_ 2048
#define H_ 1024
#define NH_ 16
#define HD_ 64

using short8 = __attribute__((__ext_vector_type__(8))) short;
using f32x4 = __attribute__((__ext_vector_type__(4))) float;
using f32x16 = __attribute__((__ext_vector_type__(16))) float;
typedef unsigned short u16;
typedef unsigned int u32;

__device__ __forceinline__ u16 f2bf(float f) {
  union { float f; unsigned u; } x{f};
  unsigned u = x.u;
  u = u + 0x7FFFu + ((u >> 16) & 1u);  // round-to-nearest-even
  return (u16)(u >> 16);
}

__device__ __forceinline__ void gld16(const void* g, void* l) {
  __builtin_amdgcn_global_load_lds(
      (const __attribute__((address_space(1))) void*)g,
      (__attribute__((address_space(3))) void*)l, 16, 0, 0);
}

#define MFMA16(a, b, c) __builtin_amdgcn_mfma_f32_16x16x32_bf16((a), (b), (c), 0, 0, 0)
#define MFMA32(a, b, c) __builtin_amdgcn_mfma_f32_32x32x16_bf16((a), (b), (c), 0, 0, 0)

// ---------------- fused cast: hs|Wq|Wk|Wv|Wo -> bf16 (contiguous dst), delta prescale ----------------
__global__ void cast_all(const float* __restrict__ hs, const float* __restrict__ Wq,
                         const float* __restrict__ Wk, const float* __restrict__ Wv,
                         const float* __restrict__ Wo, const float* __restrict__ delta,
                         u16* __restrict__ dst, float* __restrict__ dsc) {
  const int t = blockIdx.x * 256 + threadIdx.x;
  const int i = t * 4;
  const float* src;
  int off;
  if (i < 4194304) {
    src = hs; off = i;
  } else {
    const int j = i - 4194304;
    const int w = j >> 20;
    off = j & 1048575;
    src = (w == 0) ? Wq : (w == 1) ? Wk : (w == 2) ? Wv : Wo;
  }
  float4 v = *(const float4*)(src + off);
  *(ushort4*)(dst + i) = make_ushort4(f2bf(v.x), f2bf(v.y), f2bf(v.z), f2bf(v.w));
  if (t < 4096) dsc[t] = delta[t] * 0.18033688011112042f;  // 0.125*log2(e)
}

// ---------------- fused QKV GEMM: [4096,1024] x [3072,1024]^T ----------------
// q (pre-scaled by tau*0.125*log2e), k written [b,h,l,d]; v written transposed [b,h,d,l]
__global__ __launch_bounds__(256) void gemm_qkv(
    const u16* __restrict__ A, const u16* __restrict__ W,
    const float* __restrict__ bq, const float* __restrict__ bk, const float* __restrict__ bv,
    const float* __restrict__ tau,
    u16* __restrict__ qg, u16* __restrict__ kg, u16* __restrict__ vTg) {
  __shared__ u16 As[128 * 64];
  __shared__ u16 Bs[128 * 64];
  const int tid = threadIdx.x;
  const int lane = tid & 63;
  const int wave = tid >> 6;
  const int wrow = (wave >> 1) * 64;
  const int wcol = (wave & 1) * 64;
  const int m0 = blockIdx.y * 128;
  const int n0 = blockIdx.x * 128;
  const int rr = tid >> 3;
  const int c8 = (tid & 7) * 8;
  f32x4 acc[4][4] = {};
  for (int kt = 0; kt < 1024; kt += 64) {
#pragma unroll
    for (int i = 0; i < 4; i++) {
      gld16(A + (size_t)(m0 + i * 32 + rr) * 1024 + kt + c8, (char*)As + i * 4096 + wave * 1024);
      gld16(W + (size_t)(n0 + i * 32 + rr) * 1024 + kt + c8, (char*)Bs + i * 4096 + wave * 1024);
    }
    __syncthreads();
#pragma unroll
    for (int kc = 0; kc < 2; kc++) {
      const int ko = kc * 32 + (lane >> 4) * 8;
      short8 af[4], bf[4];
#pragma unroll
      for (int mi = 0; mi < 4; mi++)
        af[mi] = *(const short8*)&As[(wrow + mi * 16 + (lane & 15)) * 64 + ko];
#pragma unroll
      for (int ni = 0; ni < 4; ni++)
        bf[ni] = *(const short8*)&Bs[(wcol + ni * 16 + (lane & 15)) * 64 + ko];
#pragma unroll
      for (int mi = 0; mi < 4; mi++)
#pragma unroll
        for (int ni = 0; ni < 4; ni++)
          acc[mi][ni] = MFMA16(af[mi], bf[ni], acc[mi][ni]);
    }
    __syncthreads();
  }
  const int which = n0 >> 10;  // 0=q 1=k 2=v, uniform per block
  const int b_blk = m0 >> 11;
  const float scl = (which == 0) ? tau[b_blk] * 0.18033688011112042f : 1.0f;
  const float* bias = which == 0 ? bq : (which == 1 ? bk : bv);
#pragma unroll
  for (int ni = 0; ni < 4; ni++) {
    const int n = n0 + wcol + ni * 16 + (lane & 15);
    const int nn = n & 1023;
    const int h = nn >> 6, d = nn & 63;
    const float bb = bias[nn];
#pragma unroll
    for (int mi = 0; mi < 4; mi++) {
      const int mb = m0 + wrow + mi * 16 + ((lane >> 4) << 2);
      const int b = mb >> 11;
      const int lq = mb & 2047;
      if (which == 2) {
        ushort4 pk = make_ushort4(f2bf(acc[mi][ni][0] + bb), f2bf(acc[mi][ni][1] + bb),
                                  f2bf(acc[mi][ni][2] + bb), f2bf(acc[mi][ni][3] + bb));
        *(ushort4*)&vTg[((size_t)(b * NH_ + h) * HD_ + d) * L_ + lq] = pk;
      } else {
        u16* dst = which == 0 ? qg : kg;
#pragma unroll
        for (int r = 0; r < 4; r++)
          dst[((size_t)(b * NH_ + h) * L_ + lq + r) * HD_ + d] = f2bf((acc[mi][ni][r] + bb) * scl);
      }
    }
  }
}

// ---------------- flash attention, swapped-QK^T 32x32x16 (R2 structure) ----------------
// grid (16,32) XCD-swizzled; 256 threads; each wave owns 32 q-rows x all keys, KVBLK=64 dbuf.
__global__ __launch_bounds__(256) void attn(
    const u16* __restrict__ qg, const u16* __restrict__ kg, const u16* __restrict__ vTg,
    const float* __restrict__ dsc, u16* __restrict__ ctxg) {
  // per buffer: 8 K blocks (2 ktile x 4 ks) + 8 V blocks (2 kt x 2 dt x 2 ks2), 1KB each
  __shared__ u16 lds[2][8192];
  const int tid = threadIdx.x;
  const int lane = tid & 63;
  const int wv = tid >> 6;
  const int lane31 = lane & 31;
  const int hi = lane >> 5;
  // bijective XCD-chunk swizzle: nwg=512 -> 64 consecutive wgids (4 bh) per XCD
  const int orig = blockIdx.y * 16 + blockIdx.x;
  const int wgid = (orig & 7) * 64 + (orig >> 3);
  const int bh = wgid >> 4;
  const int qblk = wgid & 15;
  const int b = bh >> 4;
  const int h = bh & 15;
  const int q0 = qblk * 128 + wv * 32;
  const u16* qb = qg + (size_t)bh * L_ * HD_;
  const u16* kb = kg + (size_t)bh * L_ * HD_;
  const u16* vb = vTg + (size_t)bh * HD_ * L_;
  const float* db = dsc + (size_t)b * L_;

  // Q fragments (B-operand): lane holds Q[q0+lane31][ks*16 + hi*8 .. +7]
  short8 qf[4];
#pragma unroll
  for (int ks = 0; ks < 4; ks++)
    qf[ks] = *(const short8*)&qb[(size_t)(q0 + lane31) * 64 + ks * 16 + hi * 8];

  // ones A-fragment: row d=0 all-ones -> l accumulates in acc_l row 0 (hi=0,r=0 lanes)
  union { u32 u[4]; short8 s; } onesu;
  const u32 ow = (lane31 == 0) ? 0x3F803F80u : 0u;
  onesu.u[0] = ow; onesu.u[1] = ow; onesu.u[2] = ow; onesu.u[3] = ow;
  const short8 onesf = onesu.s;

  f32x16 acc[2] = {};   // ctx^T: [dtile] rows d=crow(r,hi), col q=lane31
  f32x16 accl = {};     // row 0 = running softmax denominator per q
  float mrun = -__builtin_inff();

  const int i0 = 2 * wv, i1 = 2 * wv + 1;  // this wave's staging blocks

#define STAGE(bufi, j0)                                                                   \
  {                                                                                       \
    u16* bp = lds[bufi];                                                                  \
    {                                                                                     \
      const int kt = i0 >> 2, ks = i0 & 3;                                                \
      gld16(kb + (size_t)((j0) + kt * 32 + lane31) * 64 + ks * 16 + hi * 8,               \
            bp + i0 * 512 + lane * 8);                                                    \
    }                                                                                     \
    {                                                                                     \
      const int kt = i1 >> 2, ks = i1 & 3;                                                \
      gld16(kb + (size_t)((j0) + kt * 32 + lane31) * 64 + ks * 16 + hi * 8,               \
            bp + i1 * 512 + lane * 8);                                                    \
    }                                                                                     \
    {                                                                                     \
      const int kt = i0 >> 2, dt = (i0 >> 1) & 1, ks2 = i0 & 1;                           \
      gld16(vb + (size_t)(dt * 32 + lane31) * L_ + (j0) + kt * 32 + ks2 * 16 + hi * 8,    \
            bp + (8 + i0) * 512 + lane * 8);                                              \
    }                                                                                     \
    {                                                                                     \
      const int kt = i1 >> 2, dt = (i1 >> 1) & 1, ks2 = i1 & 1;                           \
      gld16(vb + (size_t)(dt * 32 + lane31) * L_ + (j0) + kt * 32 + ks2 * 16 + hi * 8,    \
            bp + (8 + i1) * 512 + lane * 8);                                              \
    }                                                                                     \
  }

  STAGE(0, 0);
  __syncthreads();
  int cur = 0;
  for (int jt = 0; jt < L_ / 64; jt++) {
    const int j0 = jt * 64;
    if (jt + 1 < L_ / 64) STAGE(cur ^ 1, j0 + 64);
    const u16* bp = lds[cur];
#pragma unroll
    for (int kt = 0; kt < 2; kt++) {
      // S^T = K . Q^T : lane holds col q=lane31, rows key=crow(r,hi)
      f32x16 s = {};
      __builtin_amdgcn_s_setprio(1);
#pragma unroll
      for (int ks = 0; ks < 4; ks++) {
        short8 kf = *(const short8*)&bp[(kt * 4 + ks) * 512 + lane * 8];
        s = MFMA32(kf, qf[ks], s);
      }
      __builtin_amdgcn_s_setprio(0);
      // add pre-scaled delta (log2 units)
      float sv[16];
#pragma unroll
      for (int g = 0; g < 4; g++) {
        float4 dl = *(const float4*)&db[j0 + kt * 32 + g * 8 + hi * 4];
        sv[g * 4 + 0] = s[g * 4 + 0] + dl.x;
        sv[g * 4 + 1] = s[g * 4 + 1] + dl.y;
        sv[g * 4 + 2] = s[g * 4 + 2] + dl.z;
        sv[g * 4 + 3] = s[g * 4 + 3] + dl.w;
      }
      // row max (15 local + 1 cross-half shuffle)
      float t0 = fmaxf(fmaxf(sv[0], sv[1]), fmaxf(sv[2], sv[3]));
      float t1 = fmaxf(fmaxf(sv[4], sv[5]), fmaxf(sv[6], sv[7]));
      float t2 = fmaxf(fmaxf(sv[8], sv[9]), fmaxf(sv[10], sv[11]));
      float t3 = fmaxf(fmaxf(sv[12], sv[13]), fmaxf(sv[14], sv[15]));
      float pmax = fmaxf(fmaxf(t0, t1), fmaxf(t2, t3));
      pmax = fmaxf(pmax, __shfl_xor(pmax, 32));
      // defer-max (THR = 8 * log2e ~ 11.54)
      if (!__all(pmax - mrun <= 11.5f)) {
        float mnew = fmaxf(mrun, pmax);
        float al = __builtin_amdgcn_exp2f(mrun - mnew);
        mrun = mnew;
        accl[0] *= al;
#pragma unroll
        for (int dt = 0; dt < 2; dt++)
#pragma unroll
          for (int r = 0; r < 16; r++) acc[dt][r] *= al;
      }
      float p[16];
#pragma unroll
      for (int r = 0; r < 16; r++) p[r] = __builtin_amdgcn_exp2f(sv[r] - mrun);
      // T12: pack to bf16 pairs, permlane32_swap to build PV B-fragments in-register
      u32 pk[8];
#pragma unroll
      for (int i = 0; i < 8; i++)
        asm("v_cvt_pk_bf16_f32 %0, %1, %2" : "=v"(pk[i]) : "v"(p[2 * i]), "v"(p[2 * i + 1]));
      asm volatile("v_permlane32_swap_b32 %0, %1" : "+v"(pk[0]), "+v"(pk[2]));
      asm volatile("v_permlane32_swap_b32 %0, %1" : "+v"(pk[1]), "+v"(pk[3]));
      asm volatile("v_permlane32_swap_b32 %0, %1" : "+v"(pk[4]), "+v"(pk[6]));
      asm volatile("v_permlane32_swap_b32 %0, %1" : "+v"(pk[5]), "+v"(pk[7]));
      union U8 { u32 u[4]; short8 s; } f0, f1;
      f0.u[0] = pk[0]; f0.u[1] = pk[1]; f0.u[2] = pk[2]; f0.u[3] = pk[3];
      f1.u[0] = pk[4]; f1.u[1] = pk[5]; f1.u[2] = pk[6]; f1.u[3] = pk[7];
      // ctx^T += V^T . P ; accl += ones_row0 . P (softmax denominator via MFMA)
      __builtin_amdgcn_s_setprio(1);
#pragma unroll
      for (int ks2 = 0; ks2 < 2; ks2++) {
        short8 pf = ks2 ? f1.s : f0.s;
#pragma unroll
        for (int dt = 0; dt < 2; dt++) {
          short8 vf = *(const short8*)&bp[(8 + kt * 4 + dt * 2 + ks2) * 512 + lane * 8];
          acc[dt] = MFMA32(vf, pf, acc[dt]);
        }
        accl = MFMA32(onesf, pf, accl);
      }
      __builtin_amdgcn_s_setprio(0);
    }
    __syncthreads();
    cur ^= 1;
  }

  // epilogue: transpose ctx^T -> ctx via swizzled per-wave LDS tile, coalesced store
  __syncthreads();
  u16* tw = lds[0] + wv * 2048;  // 4KB per wave: [32 q][64 d] bf16, XOR-swizzled
  const float l0 = accl[0];
  const float l1 = __shfl_xor(l0, 32);
  const float inv = 1.0f / (hi ? l1 : l0);
#pragma unroll
  for (int dt = 0; dt < 2; dt++)
#pragma unroll
    for (int g = 0; g < 4; g++) {
      ushort4 w4 = make_ushort4(f2bf(acc[dt][g * 4 + 0] * inv), f2bf(acc[dt][g * 4 + 1] * inv),
                                f2bf(acc[dt][g * 4 + 2] * inv), f2bf(acc[dt][g * 4 + 3] * inv));
      const int d0 = dt * 32 + g * 8 + hi * 4;
      const int byte = (lane31 * 128 + d0 * 2) ^ ((lane31 & 15) << 3);
      *(ushort4*)((char*)tw + byte) = w4;
    }
  asm volatile("s_waitcnt lgkmcnt(0)" ::: "memory");
  const size_t obase = ((size_t)b * L_ + q0) * 1024 + h * 64;
#pragma unroll
  for (int i = 0; i < 16; i++) {
    const int qr = 2 * i + hi;
    const int byte = (qr * 128 + lane31 * 4) ^ ((qr & 15) << 3);
    const u32 val = *(const u32*)((const char*)tw + byte);
    *(u32*)&ctxg[obase + (size_t)qr * 1024 + lane31 * 2] = val;
  }
}

// ---------------- output GEMM: ctx[4096,1024] x Wo[1024,1024]^T + bo -> f32 ----------------
__global__ __launch_bounds__(256) void gemm_out(
    const u16* __restrict__ A, const u16* __restrict__ W,
    const float* __restrict__ bo, float* __restrict__ out) {
  __shared__ u16 As[128 * 64];
  __shared__ u16 Bs[128 * 64];
  const int tid = threadIdx.x;
  const int lane = tid & 63;
  const int wave = tid >> 6;
  const int wrow = (wave >> 1) * 64;
  const int wcol = (wave & 1) * 64;
  const int m0 = blockIdx.y * 128;
  const int n0 = blockIdx.x * 128;
  const int rr = tid >> 3;
  const int c8 = (tid & 7) * 8;
  f32x4 acc[4][4] = {};
  for (int kt = 0; kt < 1024; kt += 64) {
#pragma unroll
    for (int i = 0; i < 4; i++) {
      gld16(A + (size_t)(m0 + i * 32 + rr) * 1024 + kt + c8, (char*)As + i * 4096 + wave * 1024);
      gld16(W + (size_t)(n0 + i * 32 + rr) * 1024 + kt + c8, (char*)Bs + i * 4096 + wave * 1024);
    }
    __syncthreads();
#pragma unroll
    for (int kc = 0; kc < 2; kc++) {
      const int ko = kc * 32 + (lane >> 4) * 8;
      short8 af[4], bf[4];
#pragma unroll
      for (int mi = 0; mi < 4; mi++)
        af[mi] = *(const short8*)&As[(wrow + mi * 16 + (lane & 15)) * 64 + ko];
#pragma unroll
      for (int ni = 0; ni < 4; ni++)
        bf[ni] = *(const short8*)&Bs[(wcol + ni * 16 + (lane & 15)) * 64 + ko];
#pragma unroll
      for (int mi = 0; mi < 4; mi++)
#pragma unroll
        for (int ni = 0; ni < 4; ni++)
          acc[mi][ni] = MFMA16(af[mi], bf[ni], acc[mi][ni]);
    }
    __syncthreads();
  }
#pragma unroll
  for (int ni = 0; ni < 4; ni++) {
    const int n = n0 + wcol + ni * 16 + (lane & 15);
    const float bb = bo[n];
#pragma unroll
    for (int mi = 0; mi < 4; mi++) {
      const int mb = m0 + wrow + mi * 16 + ((lane >> 4) << 2);
#pragma unroll
      for (int r = 0; r < 4; r++)
        out[(size_t)(mb + r) * 1024 + n] = acc[mi][ni][r] + bb;
    }
  }
}

extern "C" void kernel_launch(void* const* d_in, const int* in_sizes, int n_in,
                              void* d_out, int out_size, void* d_ws, size_t ws_size,
                              hipStream_t stream) {
  const float* hs = (const float*)d_in[0];
  const float* tau = (const float*)d_in[1];
  const float* delta = (const float*)d_in[2];
  const float* Wq = (const float*)d_in[3];
  const float* bq = (const float*)d_in[4];
  const float* Wk = (const float*)d_in[5];
  const float* bk = (const float*)d_in[6];
  const float* Wv = (const float*)d_in[7];
  const float* bv = (const float*)d_in[8];
  const float* Wo = (const float*)d_in[9];
  const float* bo = (const float*)d_in[10];
  float* out = (float*)d_out;

  u16* ws = (u16*)d_ws;
  u16* hsb  = ws;                   // 4194304
  u16* wqkv = ws + 4194304;         // 3145728 (Wq|Wk|Wv)
  u16* wob  = ws + 7340032;         // 1048576
  u16* qg   = ws + 8388608;         // 4194304
  u16* kg   = ws + 12582912;        // 4194304
  u16* vTg  = ws + 16777216;        // 4194304
  u16* ctxg = ws + 20971520;        // 4194304
  float* dsc = (float*)(ws + 25165824);  // 4096 floats

  cast_all<<<8192, 256, 0, stream>>>(hs, Wq, Wk, Wv, Wo, delta, ws, dsc);

  gemm_qkv<<<dim3(24, 32), 256, 0, stream>>>(hsb, wqkv, bq, bk, bv, tau, qg, kg, vTg);
  attn<<<dim3(16, 32), 256, 0, stream>>>(qg, kg, vTg, dsc, ctxg);
  gemm_out<<<dim3(8, 32), 256, 0, stream>>>(ctxg, wob, bo, out);
}